// Round 5
// baseline (2271.900 us; speedup 1.0000x reference)
//
#include <hip/hip_runtime.h>
#include <cstdint>
#include <cstddef>

typedef unsigned short u16;
typedef __attribute__((ext_vector_type(8))) short short8;
typedef __attribute__((ext_vector_type(4))) float f32x4;

#define DEV __device__ __forceinline__

DEV float bf2f(u16 u) {
    union { float f; uint32_t i; } c; c.i = ((uint32_t)u) << 16; return c.f;
}
DEV u16 f2bf(float f) {
    union { float f; uint32_t i; } c; c.f = f;
    uint32_t r = c.i + 0x7FFF + ((c.i >> 16) & 1);
    return (u16)(r >> 16);
}

DEV void gload16(const void* g, void* l) {
    __builtin_amdgcn_global_load_lds(
        (const __attribute__((address_space(1))) void*)g,
        (__attribute__((address_space(3))) void*)l, 16, 0, 0);
}

// ---------------------------------------------------------------------------
// GEMM: C[M,N] = A[M,K] * Bt[N,K]^T  (+ epilogue)
// EPI 0: bf16 out = acc + bias[n]
// EPI 1: f32 out  = acc + bias[n] + resid[row*ldc+col]
// EPI 2: bf16 out = gelu_exact(acc + bias[n])
// EPI 3: bf16 out = acc * scale          (attention scores)
// EPI 4: bf16 out = acc                  (PV context)
// NOTE: reference reshapes (B,L,D)->(B,H,L,DH) with NO transpose; heads are
// contiguous flat [512,64] chunks (lda=64). Attention GEMMs use that layout.
// ---------------------------------------------------------------------------
template<int WM, int WN, int MR, int NR, int EPI>
__global__ __launch_bounds__(256)
void gemm_bt(const u16* __restrict__ A, const u16* __restrict__ B, void* __restrict__ C,
             const float* __restrict__ bias, const float* __restrict__ resid,
             int K, int lda, int ldb, int ldc,
             int nh, long a_zb, long a_zh, long b_zb, long b_zh, long c_zb, long c_zh,
             float scale)
{
    static_assert(WM * WN == 4, "4 waves");
    constexpr int BM = WM * MR * 16;
    constexpr int BN = WN * NR * 16;
    constexpr int BK = 32;
    __shared__ __align__(16) u16 As[BM * BK];
    __shared__ __align__(16) u16 Bs[BN * BK];

    const int tid  = threadIdx.x;
    const int lane = tid & 63;
    const int wid  = tid >> 6;
    const int zz = blockIdx.z;
    const int b = zz / nh, h = zz % nh;
    A += (long)b * a_zb + (long)h * a_zh;
    B += (long)b * b_zb + (long)h * b_zh;
    const long coff = (long)b * c_zb + (long)h * c_zh;
    const int m0 = blockIdx.x * BM, n0 = blockIdx.y * BN;

    f32x4 acc[MR][NR] = {};
    constexpr int AI = (BM * 4) / 256;   // 16B chunks per tile / threads
    constexpr int BI = (BN * 4) / 256;

    const int wr = wid / WN, wc = wid % WN;
    const int lr = lane & 15, lk = lane >> 4;

    for (int k0 = 0; k0 < K; k0 += BK) {
#pragma unroll
        for (int i = 0; i < AI; ++i) {
            int ch = (i << 8) + tid;
            const u16* g = A + (long)(m0 + (ch >> 2)) * lda + k0 + ((ch & 3) << 3);
            gload16(g, (char*)As + ch * 16);
        }
#pragma unroll
        for (int i = 0; i < BI; ++i) {
            int ch = (i << 8) + tid;
            const u16* g = B + (long)(n0 + (ch >> 2)) * ldb + k0 + ((ch & 3) << 3);
            gload16(g, (char*)Bs + ch * 16);
        }
        asm volatile("s_waitcnt vmcnt(0)" ::: "memory");
        __syncthreads();

        short8 af[MR], bf[NR];
#pragma unroll
        for (int m = 0; m < MR; ++m)
            af[m] = *(const short8*)(As + (wr * MR * 16 + m * 16 + lr) * BK + lk * 8);
#pragma unroll
        for (int n = 0; n < NR; ++n)
            bf[n] = *(const short8*)(Bs + (wc * NR * 16 + n * 16 + lr) * BK + lk * 8);
#pragma unroll
        for (int m = 0; m < MR; ++m)
#pragma unroll
            for (int n = 0; n < NR; ++n)
                acc[m][n] = __builtin_amdgcn_mfma_f32_16x16x32_bf16(af[m], bf[n], acc[m][n], 0, 0, 0);
        __syncthreads();
    }

    // epilogue: D lane layout: col = lane&15, row = (lane>>4)*4 + j
#pragma unroll
    for (int m = 0; m < MR; ++m) {
        const int rowb = m0 + wr * MR * 16 + m * 16 + (lane >> 4) * 4;
#pragma unroll
        for (int n = 0; n < NR; ++n) {
            const int col = n0 + wc * NR * 16 + n * 16 + lr;
            float bv = 0.f;
            if (EPI == 0 || EPI == 1 || EPI == 2) bv = bias[col];
#pragma unroll
            for (int j = 0; j < 4; ++j) {
                const long idx = coff + (long)(rowb + j) * ldc + col;
                float v = acc[m][n][j];
                if (EPI == 0) {
                    ((u16*)C)[idx] = f2bf(v + bv);
                } else if (EPI == 1) {
                    ((float*)C)[idx] = v + bv + resid[(long)(rowb + j) * ldc + col];
                } else if (EPI == 2) {
                    float t = v + bv;
                    ((u16*)C)[idx] = f2bf(0.5f * t * (1.0f + erff(t * 0.70710678118654752f)));
                } else if (EPI == 3) {
                    ((u16*)C)[idx] = f2bf(v * scale);
                } else {
                    ((u16*)C)[idx] = f2bf(v);
                }
            }
        }
    }
}

// ---------------------------------------------------------------------------
// weight transpose + f32->bf16: src fp32 [K,N] tile -> dst bf16 [row_off+N, K]
// ---------------------------------------------------------------------------
__global__ __launch_bounds__(256)
void wconv_kernel(const float* __restrict__ src, u16* __restrict__ dst,
                  int K, int N, int row_off)
{
    __shared__ __align__(16) float t[64][65];
    const float* s = src + (long)(blockIdx.y * 64) * N + blockIdx.x * 64;
    const int tid = threadIdx.x;
#pragma unroll
    for (int i = 0; i < 4; ++i) {
        int ch = (i << 8) + tid;
        int r = ch >> 4, c4 = ch & 15;
        float4 v = *(const float4*)(s + (long)r * N + c4 * 4);
        t[r][c4 * 4 + 0] = v.x; t[r][c4 * 4 + 1] = v.y;
        t[r][c4 * 4 + 2] = v.z; t[r][c4 * 4 + 3] = v.w;
    }
    __syncthreads();
    u16* d = dst + (long)(row_off + blockIdx.x * 64) * K + blockIdx.y * 64;
#pragma unroll
    for (int i = 0; i < 4; ++i) {
        int ch = (i << 8) + tid;
        int c = ch >> 4, k4 = ch & 15;
        ushort4 o;
        o.x = f2bf(t[k4 * 4 + 0][c]);
        o.y = f2bf(t[k4 * 4 + 1][c]);
        o.z = f2bf(t[k4 * 4 + 2][c]);
        o.w = f2bf(t[k4 * 4 + 3][c]);
        *(ushort4*)(d + (long)c * K + k4 * 4) = o;
    }
}

// ---------------------------------------------------------------------------
// embedding: x = tok_emb[seq] + PE + seg_emb[seg]; writes f32 + bf16
// ---------------------------------------------------------------------------
__global__ __launch_bounds__(256)
void embed_kernel(const int* __restrict__ seq, const int* __restrict__ seg,
                  const float* __restrict__ tok, const float* __restrict__ sege,
                  float* __restrict__ x, u16* __restrict__ xb)
{
    long i = ((long)blockIdx.x << 8) + threadIdx.x;  // B*L*512 pairs
    int d2 = (int)(i & 511);
    long bl = i >> 9;
    int l = (int)(bl & 511);
    int t = seq[bl];
    int g = seg[bl];
    float div = powf(10000.f, -(float)(2 * d2) * (1.0f / 1024.f));
    float arg = (float)l * div;
    float sv = sinf(arg), cv = cosf(arg);
    long toff = (long)t * 1024 + 2 * d2;
    long goff = (long)g * 1024 + 2 * d2;
    float x0 = tok[toff]     + sv + sege[goff];
    float x1 = tok[toff + 1] + cv + sege[goff + 1];
    long xo = (bl << 10) + 2 * d2;
    x[xo] = x0; x[xo + 1] = x1;
    xb[xo] = f2bf(x0); xb[xo + 1] = f2bf(x1);
}

// ---------------------------------------------------------------------------
// per-head V transpose: Vb flat per (b,h) = [512,64] row-major contiguous
//   -> vt per (b,h) = [64,512]
// ---------------------------------------------------------------------------
__global__ __launch_bounds__(256)
void vtrans_kernel(const u16* __restrict__ Vb, u16* __restrict__ vt)
{
    __shared__ __align__(16) u16 t[64][72];
    const int bh = blockIdx.y;           // 0..127
    const int l0 = blockIdx.x << 6;      // 0,64,...,448
    const u16* src = Vb + ((long)bh << 15) + (long)l0 * 64;   // contiguous 64x64
    const int tid = threadIdx.x;
#pragma unroll
    for (int i = 0; i < 2; ++i) {
        int ch = (i << 8) + tid;         // 0..511, 8 elems each
        int r = ch >> 3, c8 = ch & 7;
        short8 v = *(const short8*)(src + (long)r * 64 + (c8 << 3));
#pragma unroll
        for (int j = 0; j < 8; ++j) t[r][(c8 << 3) + j] = (u16)v[j];
    }
    __syncthreads();
    u16* d = vt + ((long)bh << 15) + l0;
#pragma unroll
    for (int i = 0; i < 2; ++i) {
        int ch = (i << 8) + tid;
        int dd = ch >> 3, l8 = ch & 7;
        short8 o;
#pragma unroll
        for (int j = 0; j < 8; ++j) o[j] = (short)t[(l8 << 3) + j][dd];
        *(short8*)(d + (long)dd * 512 + (l8 << 3)) = o;
    }
}

// ---------------------------------------------------------------------------
// masked softmax over rows of S [B*H*L, 512], bf16 in-place. one wave per row
// mask: key index k is the reshaped axis; reference masks seq[b, k] == 0
// ---------------------------------------------------------------------------
__global__ __launch_bounds__(256)
void softmax_kernel(u16* __restrict__ S, const int* __restrict__ seq)
{
    long row = ((long)blockIdx.x << 2) + (threadIdx.x >> 6);
    int lane = threadIdx.x & 63;
    int b = (int)(row >> 13);   // / (H*L = 8192)
    u16* p = S + (row << 9);
    short8 raw = *(short8*)(p + (lane << 3));
    const int* sq = seq + (b << 9) + (lane << 3);
    float v[8];
#pragma unroll
    for (int i = 0; i < 8; ++i)
        v[i] = (sq[i] == 0) ? -1e9f : bf2f((u16)raw[i]);
    float mx = v[0];
#pragma unroll
    for (int i = 1; i < 8; ++i) mx = fmaxf(mx, v[i]);
#pragma unroll
    for (int o = 32; o; o >>= 1) mx = fmaxf(mx, __shfl_xor(mx, o));
    float e[8], sum = 0.f;
#pragma unroll
    for (int i = 0; i < 8; ++i) { e[i] = expf(v[i] - mx); sum += e[i]; }
#pragma unroll
    for (int o = 32; o; o >>= 1) sum += __shfl_xor(sum, o);
    float r = 1.0f / sum;
    short8 o8;
#pragma unroll
    for (int i = 0; i < 8; ++i) o8[i] = (short)f2bf(e[i] * r);
    *(short8*)(p + (lane << 3)) = o8;
}

// ---------------------------------------------------------------------------
// LayerNorm over D=1024, block per row; writes f32 (residual stream) + bf16
// ---------------------------------------------------------------------------
__global__ __launch_bounds__(256)
void ln_kernel(const float* __restrict__ in, float* __restrict__ xout, u16* __restrict__ xbout)
{
    const int row = blockIdx.x;
    const int tid = threadIdx.x;
    const float4 v = ((const float4*)(in + (long)row * 1024))[tid];
    float s = v.x + v.y + v.z + v.w;
#pragma unroll
    for (int o = 32; o; o >>= 1) s += __shfl_down(s, o);
    __shared__ float red[8];
    const int wid = tid >> 6, lane = tid & 63;
    if (lane == 0) red[wid] = s;
    __syncthreads();
    const float mean = (red[0] + red[1] + red[2] + red[3]) * (1.0f / 1024.f);
    const float dx = v.x - mean, dy = v.y - mean, dz = v.z - mean, dw = v.w - mean;
    float q = dx * dx + dy * dy + dz * dz + dw * dw;
#pragma unroll
    for (int o = 32; o; o >>= 1) q += __shfl_down(q, o);
    if (lane == 0) red[4 + wid] = q;
    __syncthreads();
    const float var = (red[4] + red[5] + red[6] + red[7]) * (1.0f / 1024.f);
    const float inv = rsqrtf(var + 1e-5f);
    float4 o4;
    o4.x = dx * inv; o4.y = dy * inv; o4.z = dz * inv; o4.w = dw * inv;
    ((float4*)(xout + (long)row * 1024))[tid] = o4;
    ushort4 ob;
    ob.x = f2bf(o4.x); ob.y = f2bf(o4.y); ob.z = f2bf(o4.z); ob.w = f2bf(o4.w);
    ((ushort4*)(xbout + (long)row * 1024))[tid] = ob;
}

// ---------------------------------------------------------------------------
extern "C" void kernel_launch(void* const* d_in, const int* in_sizes, int n_in,
                              void* d_out, int out_size, void* d_ws, size_t ws_size,
                              hipStream_t stream)
{
    const int*   seqp = (const int*)d_in[0];
    const int*   segp = (const int*)d_in[1];
    const float* tok  = (const float*)d_in[2];
    const float* sege = (const float*)d_in[3];
    const float* Wq = (const float*)d_in[4];  const float* bq = (const float*)d_in[5];
    const float* Wk = (const float*)d_in[6];  const float* bk = (const float*)d_in[7];
    const float* Wv = (const float*)d_in[8];  const float* bv = (const float*)d_in[9];
    const float* Wo = (const float*)d_in[10]; const float* bo = (const float*)d_in[11];
    const float* W1 = (const float*)d_in[12]; const float* b1 = (const float*)d_in[13];
    const float* W2 = (const float*)d_in[14]; const float* b2 = (const float*)d_in[15];

    // ---- workspace (lifetime-aliased; ~160 MB) ----
    char* w = (char*)d_ws;
    auto take = [&](size_t bytes) -> void* {
        void* p = (void*)w; w += (bytes + 255) & ~(size_t)255; return p;
    };
    float* x    = (float*)take(4096UL * 1024 * 4);     // 16 MB residual f32
    u16*   xb   = (u16*)  take(4096UL * 1024 * 2);     //  8 MB residual bf16
    float* tmp  = (float*)take(4096UL * 1024 * 4);     // 16 MB pre-LN f32
    u16*   R1   = (u16*)  take(128UL * 512 * 512 * 2); // 64 MB: S then hbuf
    u16*   Qb   = (u16*)  take(4096UL * 1024 * 2);     //  8 MB
    u16*   Kb   = (u16*)  take(4096UL * 1024 * 2);     //  8 MB
    u16*   Vb   = (u16*)  take(4096UL * 1024 * 2);     //  8 MB
    u16*   ctx  = (u16*)  take(4096UL * 1024 * 2);     //  8 MB
    u16*   vt   = (u16*)  take(128UL * 64 * 512 * 2);  //  8 MB
    u16*   qkvw = (u16*)  take(3072UL * 1024 * 2);     //  6 MB W_{q,k,v}^T
    u16*   wo_t = (u16*)  take(1024UL * 1024 * 2);     //  2 MB
    u16*   w1_t = (u16*)  take(4096UL * 1024 * 2);     //  8 MB
    u16*   w2_t = (u16*)  take(1024UL * 4096 * 2);     //  8 MB

    u16* S    = R1;   // scores [B,H,512,512] bf16
    u16* hbuf = R1;   // FFN hidden [4096,4096] (S dead by then)

    embed_kernel<<<8192, 256, 0, stream>>>(seqp, segp, tok, sege, x, xb);

    for (int l = 0; l < 6; ++l) {
        // per-layer weight conversion (transpose + bf16)
        wconv_kernel<<<dim3(16, 16), 256, 0, stream>>>(Wq + (long)l * 1048576L, qkvw, 1024, 1024, 0);
        wconv_kernel<<<dim3(16, 16), 256, 0, stream>>>(Wk + (long)l * 1048576L, qkvw, 1024, 1024, 1024);
        wconv_kernel<<<dim3(16, 16), 256, 0, stream>>>(Wv + (long)l * 1048576L, qkvw, 1024, 1024, 2048);
        wconv_kernel<<<dim3(16, 16), 256, 0, stream>>>(Wo + (long)l * 1048576L, wo_t, 1024, 1024, 0);
        wconv_kernel<<<dim3(64, 16), 256, 0, stream>>>(W1 + (long)l * 4194304L, w1_t, 1024, 4096, 0);
        wconv_kernel<<<dim3(16, 64), 256, 0, stream>>>(W2 + (long)l * 4194304L, w2_t, 4096, 1024, 0);

        // Q/K/V projections -> separate [4096,1024] bf16 buffers
        gemm_bt<2, 2, 4, 4, 0><<<dim3(32, 8, 1), 256, 0, stream>>>(
            xb, qkvw,                Qb, bq + l * 1024, nullptr,
            1024, 1024, 1024, 1024, 1, 0, 0, 0, 0, 0, 0, 1.f);
        gemm_bt<2, 2, 4, 4, 0><<<dim3(32, 8, 1), 256, 0, stream>>>(
            xb, qkvw + 1048576L,     Kb, bk + l * 1024, nullptr,
            1024, 1024, 1024, 1024, 1, 0, 0, 0, 0, 0, 0, 1.f);
        gemm_bt<2, 2, 4, 4, 0><<<dim3(32, 8, 1), 256, 0, stream>>>(
            xb, qkvw + 2097152L,     Vb, bv + l * 1024, nullptr,
            1024, 1024, 1024, 1024, 1, 0, 0, 0, 0, 0, 0, 1.f);

        // per-head V transpose: [512,64] -> [64,512]
        vtrans_kernel<<<dim3(8, 128), 256, 0, stream>>>(Vb, vt);

        // scores per (b,h): Q2[512,64] @ K2[512,64]^T * 0.125
        // head (b,h) = contiguous flat chunk (reference's transpose-free reshape)
        gemm_bt<2, 2, 4, 4, 3><<<dim3(4, 4, 128), 256, 0, stream>>>(
            Qb, Kb, S, nullptr, nullptr,
            64, 64, 64, 512,
            16, 524288L, 32768L, 524288L, 32768L, 4194304L, 262144L, 0.125f);

        // masked softmax (in place)
        softmax_kernel<<<16384, 256, 0, stream>>>(S, seqp);

        // context per (b,h): P[512,512] @ Vt[64,512]^T -> ctx chunk [512,64]
        gemm_bt<4, 1, 2, 4, 4><<<dim3(4, 1, 128), 256, 0, stream>>>(
            S, vt, ctx, nullptr, nullptr,
            512, 512, 512, 64,
            16, 4194304L, 262144L, 524288L, 32768L, 524288L, 32768L, 1.f);

        // output projection + bias + residual -> tmp fp32
        gemm_bt<2, 2, 4, 4, 1><<<dim3(32, 8, 1), 256, 0, stream>>>(
            ctx, wo_t, tmp, bo + l * 1024, x,
            1024, 1024, 1024, 1024, 1, 0, 0, 0, 0, 0, 0, 1.f);

        // LN -> x (f32 residual) + xb (bf16)
        ln_kernel<<<4096, 256, 0, stream>>>(tmp, x, xb);

        // FFN1 + exact GELU -> hbuf bf16 [4096,4096]  (overlays dead S)
        gemm_bt<2, 2, 4, 4, 2><<<dim3(32, 32, 1), 256, 0, stream>>>(
            xb, w1_t, hbuf, b1 + l * 4096, nullptr,
            1024, 1024, 1024, 4096, 1, 0, 0, 0, 0, 0, 0, 1.f);

        // FFN2 + bias + residual -> tmp fp32
        gemm_bt<2, 2, 4, 4, 1><<<dim3(32, 8, 1), 256, 0, stream>>>(
            hbuf, w2_t, tmp, b2 + l * 1024, x,
            4096, 4096, 4096, 1024, 1, 0, 0, 0, 0, 0, 0, 1.f);

        // LN -> x / d_out
        ln_kernel<<<4096, 256, 0, stream>>>(tmp, (l == 5) ? (float*)d_out : x, xb);
    }
}

// Round 6
// 1949.068 us; speedup vs baseline: 1.1656x; 1.1656x over previous
//
#include <hip/hip_runtime.h>
#include <cstdint>
#include <cstddef>

typedef unsigned short u16;
typedef __attribute__((ext_vector_type(8))) short short8;
typedef __attribute__((ext_vector_type(4))) float f32x4;

#define DEV __device__ __forceinline__

DEV float bf2f(u16 u) {
    union { float f; uint32_t i; } c; c.i = ((uint32_t)u) << 16; return c.f;
}
DEV u16 f2bf(float f) {
    union { float f; uint32_t i; } c; c.f = f;
    uint32_t r = c.i + 0x7FFF + ((c.i >> 16) & 1);
    return (u16)(r >> 16);
}

DEV void gload16(const void* g, void* l) {
    __builtin_amdgcn_global_load_lds(
        (const __attribute__((address_space(1))) void*)g,
        (__attribute__((address_space(3))) void*)l, 16, 0, 0);
}

// ---------------------------------------------------------------------------
// GEMM: C[M,N] = A[M,K] * Bt[N,K]^T  (+ epilogue), double-buffered LDS with
// prefetch-before-compute (T3-min 2-phase pipeline).
// EPI 0: bf16 out = acc + bias[n]
// EPI 1: f32 out  = acc + bias[n] + resid[row*ldc+col]
// EPI 2: bf16 out = gelu_exact(acc + bias[n])
// EPI 3: bf16 out = acc * scale          (attention scores)
// EPI 4: bf16 out = acc                  (PV context)
// EPI 5: bf16 out = acc + bias[n], routed to 3 stacked [M,1024] buffers by
//        col>>10 (fused QKV, transpose-free head layout)
// ---------------------------------------------------------------------------
template<int WM, int WN, int MR, int NR, int EPI>
__global__ __launch_bounds__(256)
void gemm_bt(const u16* __restrict__ A, const u16* __restrict__ B, void* __restrict__ C,
             const float* __restrict__ bias, const float* __restrict__ resid,
             int K, int lda, int ldb, int ldc,
             int nh, long a_zb, long a_zh, long b_zb, long b_zh, long c_zb, long c_zh,
             float scale)
{
    static_assert(WM * WN == 4, "4 waves");
    constexpr int BM = WM * MR * 16;
    constexpr int BN = WN * NR * 16;
    constexpr int BK = 32;
    __shared__ __align__(16) u16 As[2 * BM * BK];
    __shared__ __align__(16) u16 Bs[2 * BN * BK];

    const int tid  = threadIdx.x;
    const int lane = tid & 63;
    const int wid  = tid >> 6;
    const int zz = blockIdx.z;
    const int b = zz / nh, h = zz % nh;
    A += (long)b * a_zb + (long)h * a_zh;
    B += (long)b * b_zb + (long)h * b_zh;
    const long coff = (long)b * c_zb + (long)h * c_zh;
    const int m0 = blockIdx.x * BM, n0 = blockIdx.y * BN;

    f32x4 acc[MR][NR] = {};
    constexpr int AI = (BM * 4) / 256;   // 16B chunks per tile / threads
    constexpr int BI = (BN * 4) / 256;

    const int wr = wid / WN, wc = wid % WN;
    const int lr = lane & 15, lk = lane >> 4;

    auto stage = [&](int buf, int k0) {
#pragma unroll
        for (int i = 0; i < AI; ++i) {
            int ch = (i << 8) + tid;
            const u16* g = A + (long)(m0 + (ch >> 2)) * lda + k0 + ((ch & 3) << 3);
            gload16(g, (char*)As + (size_t)buf * (BM * BK * 2) + ch * 16);
        }
#pragma unroll
        for (int i = 0; i < BI; ++i) {
            int ch = (i << 8) + tid;
            const u16* g = B + (long)(n0 + (ch >> 2)) * ldb + k0 + ((ch & 3) << 3);
            gload16(g, (char*)Bs + (size_t)buf * (BN * BK * 2) + ch * 16);
        }
    };

    // prologue: stage first K-tile
    stage(0, 0);
    asm volatile("s_waitcnt vmcnt(0)" ::: "memory");
    __syncthreads();

    int cur = 0;
    for (int k0 = 0; k0 < K; k0 += BK) {
        // prefetch next K-tile into the other buffer (hides under MFMA)
        if (k0 + BK < K) stage(cur ^ 1, k0 + BK);

        const u16* Ac = As + (size_t)cur * (BM * BK);
        const u16* Bc = Bs + (size_t)cur * (BN * BK);
        short8 af[MR], bf[NR];
#pragma unroll
        for (int m = 0; m < MR; ++m)
            af[m] = *(const short8*)(Ac + (wr * MR * 16 + m * 16 + lr) * BK + lk * 8);
#pragma unroll
        for (int n = 0; n < NR; ++n)
            bf[n] = *(const short8*)(Bc + (wc * NR * 16 + n * 16 + lr) * BK + lk * 8);
#pragma unroll
        for (int m = 0; m < MR; ++m)
#pragma unroll
            for (int n = 0; n < NR; ++n)
                acc[m][n] = __builtin_amdgcn_mfma_f32_16x16x32_bf16(af[m], bf[n], acc[m][n], 0, 0, 0);

        // drain next-tile staging; barrier also protects buf reuse next iter
        asm volatile("s_waitcnt vmcnt(0)" ::: "memory");
        __syncthreads();
        cur ^= 1;
    }

    // epilogue: D lane layout: col = lane&15, row = (lane>>4)*4 + j
#pragma unroll
    for (int m = 0; m < MR; ++m) {
        const int rowb = m0 + wr * MR * 16 + m * 16 + (lane >> 4) * 4;
#pragma unroll
        for (int n = 0; n < NR; ++n) {
            const int col = n0 + wc * NR * 16 + n * 16 + lr;
            float bv = 0.f;
            if (EPI == 0 || EPI == 1 || EPI == 2 || EPI == 5) bv = bias[col];
#pragma unroll
            for (int j = 0; j < 4; ++j) {
                const long idx = coff + (long)(rowb + j) * ldc + col;
                float v = acc[m][n][j];
                if (EPI == 0) {
                    ((u16*)C)[idx] = f2bf(v + bv);
                } else if (EPI == 1) {
                    ((float*)C)[idx] = v + bv + resid[(long)(rowb + j) * ldc + col];
                } else if (EPI == 2) {
                    float t = v + bv;
                    ((u16*)C)[idx] = f2bf(0.5f * t * (1.0f + erff(t * 0.70710678118654752f)));
                } else if (EPI == 3) {
                    ((u16*)C)[idx] = f2bf(v * scale);
                } else if (EPI == 5) {
                    const long qidx = (long)(col >> 10) * 4194304L
                                    + (long)(rowb + j) * 1024 + (col & 1023);
                    ((u16*)C)[qidx] = f2bf(v + bv);
                } else {
                    ((u16*)C)[idx] = f2bf(v);
                }
            }
        }
    }
}

// ---------------------------------------------------------------------------
// weight transpose + f32->bf16: src fp32 [K,N] tile -> dst bf16 [row_off+N, K]
// ---------------------------------------------------------------------------
__global__ __launch_bounds__(256)
void wconv_kernel(const float* __restrict__ src, u16* __restrict__ dst,
                  int K, int N, int row_off)
{
    __shared__ __align__(16) float t[64][65];
    const float* s = src + (long)(blockIdx.y * 64) * N + blockIdx.x * 64;
    const int tid = threadIdx.x;
#pragma unroll
    for (int i = 0; i < 4; ++i) {
        int ch = (i << 8) + tid;
        int r = ch >> 4, c4 = ch & 15;
        float4 v = *(const float4*)(s + (long)r * N + c4 * 4);
        t[r][c4 * 4 + 0] = v.x; t[r][c4 * 4 + 1] = v.y;
        t[r][c4 * 4 + 2] = v.z; t[r][c4 * 4 + 3] = v.w;
    }
    __syncthreads();
    u16* d = dst + (long)(row_off + blockIdx.x * 64) * K + blockIdx.y * 64;
#pragma unroll
    for (int i = 0; i < 4; ++i) {
        int ch = (i << 8) + tid;
        int c = ch >> 4, k4 = ch & 15;
        ushort4 o;
        o.x = f2bf(t[k4 * 4 + 0][c]);
        o.y = f2bf(t[k4 * 4 + 1][c]);
        o.z = f2bf(t[k4 * 4 + 2][c]);
        o.w = f2bf(t[k4 * 4 + 3][c]);
        *(ushort4*)(d + (long)c * K + k4 * 4) = o;
    }
}

__global__ __launch_bounds__(256)
void bconcat_kernel(const float* __restrict__ bq, const float* __restrict__ bk,
                    const float* __restrict__ bv, float* __restrict__ out)
{
    int i = blockIdx.x * 256 + threadIdx.x;   // 6*3072 total
    int l = i / 3072, n = i % 3072;
    float v = (n < 1024) ? bq[l * 1024 + n]
            : (n < 2048) ? bk[l * 1024 + n - 1024]
                         : bv[l * 1024 + n - 2048];
    out[i] = v;
}

// ---------------------------------------------------------------------------
// embedding: x = tok_emb[seq] + PE + seg_emb[seg]; writes f32 + bf16
// ---------------------------------------------------------------------------
__global__ __launch_bounds__(256)
void embed_kernel(const int* __restrict__ seq, const int* __restrict__ seg,
                  const float* __restrict__ tok, const float* __restrict__ sege,
                  float* __restrict__ x, u16* __restrict__ xb)
{
    long i = ((long)blockIdx.x << 8) + threadIdx.x;  // B*L*512 pairs
    int d2 = (int)(i & 511);
    long bl = i >> 9;
    int l = (int)(bl & 511);
    int t = seq[bl];
    int g = seg[bl];
    float div = powf(10000.f, -(float)(2 * d2) * (1.0f / 1024.f));
    float arg = (float)l * div;
    float sv = sinf(arg), cv = cosf(arg);
    long toff = (long)t * 1024 + 2 * d2;
    long goff = (long)g * 1024 + 2 * d2;
    float x0 = tok[toff]     + sv + sege[goff];
    float x1 = tok[toff + 1] + cv + sege[goff + 1];
    long xo = (bl << 10) + 2 * d2;
    x[xo] = x0; x[xo + 1] = x1;
    xb[xo] = f2bf(x0); xb[xo + 1] = f2bf(x1);
}

// ---------------------------------------------------------------------------
// per-head V transpose: Vb flat per (b,h) = [512,64] row-major contiguous
//   -> vt per (b,h) = [64,512]
// ---------------------------------------------------------------------------
__global__ __launch_bounds__(256)
void vtrans_kernel(const u16* __restrict__ Vb, u16* __restrict__ vt)
{
    __shared__ __align__(16) u16 t[64][72];
    const int bh = blockIdx.y;           // 0..127
    const int l0 = blockIdx.x << 6;      // 0,64,...,448
    const u16* src = Vb + ((long)bh << 15) + (long)l0 * 64;   // contiguous 64x64
    const int tid = threadIdx.x;
#pragma unroll
    for (int i = 0; i < 2; ++i) {
        int ch = (i << 8) + tid;         // 0..511, 8 elems each
        int r = ch >> 3, c8 = ch & 7;
        short8 v = *(const short8*)(src + (long)r * 64 + (c8 << 3));
#pragma unroll
        for (int j = 0; j < 8; ++j) t[r][(c8 << 3) + j] = (u16)v[j];
    }
    __syncthreads();
    u16* d = vt + ((long)bh << 15) + l0;
#pragma unroll
    for (int i = 0; i < 2; ++i) {
        int ch = (i << 8) + tid;
        int dd = ch >> 3, l8 = ch & 7;
        short8 o;
#pragma unroll
        for (int j = 0; j < 8; ++j) o[j] = (short)t[(l8 << 3) + j][dd];
        *(short8*)(d + (long)dd * 512 + (l8 << 3)) = o;
    }
}

// ---------------------------------------------------------------------------
// masked softmax over rows of S [B*H*L, 512], bf16 in-place. one wave per row
// ---------------------------------------------------------------------------
__global__ __launch_bounds__(256)
void softmax_kernel(u16* __restrict__ S, const int* __restrict__ seq)
{
    long row = ((long)blockIdx.x << 2) + (threadIdx.x >> 6);
    int lane = threadIdx.x & 63;
    int b = (int)(row >> 13);   // / (H*L = 8192)
    u16* p = S + (row << 9);
    short8 raw = *(short8*)(p + (lane << 3));
    const int* sq = seq + (b << 9) + (lane << 3);
    float v[8];
#pragma unroll
    for (int i = 0; i < 8; ++i)
        v[i] = (sq[i] == 0) ? -1e9f : bf2f((u16)raw[i]);
    float mx = v[0];
#pragma unroll
    for (int i = 1; i < 8; ++i) mx = fmaxf(mx, v[i]);
#pragma unroll
    for (int o = 32; o; o >>= 1) mx = fmaxf(mx, __shfl_xor(mx, o));
    float e[8], sum = 0.f;
#pragma unroll
    for (int i = 0; i < 8; ++i) { e[i] = expf(v[i] - mx); sum += e[i]; }
#pragma unroll
    for (int o = 32; o; o >>= 1) sum += __shfl_xor(sum, o);
    float r = 1.0f / sum;
    short8 o8;
#pragma unroll
    for (int i = 0; i < 8; ++i) o8[i] = (short)f2bf(e[i] * r);
    *(short8*)(p + (lane << 3)) = o8;
}

// ---------------------------------------------------------------------------
// LayerNorm over D=1024, block per row; writes f32 (residual stream) + bf16
// ---------------------------------------------------------------------------
__global__ __launch_bounds__(256)
void ln_kernel(const float* __restrict__ in, float* __restrict__ xout, u16* __restrict__ xbout)
{
    const int row = blockIdx.x;
    const int tid = threadIdx.x;
    const float4 v = ((const float4*)(in + (long)row * 1024))[tid];
    float s = v.x + v.y + v.z + v.w;
#pragma unroll
    for (int o = 32; o; o >>= 1) s += __shfl_down(s, o);
    __shared__ float red[8];
    const int wid = tid >> 6, lane = tid & 63;
    if (lane == 0) red[wid] = s;
    __syncthreads();
    const float mean = (red[0] + red[1] + red[2] + red[3]) * (1.0f / 1024.f);
    const float dx = v.x - mean, dy = v.y - mean, dz = v.z - mean, dw = v.w - mean;
    float q = dx * dx + dy * dy + dz * dz + dw * dw;
#pragma unroll
    for (int o = 32; o; o >>= 1) q += __shfl_down(q, o);
    if (lane == 0) red[4 + wid] = q;
    __syncthreads();
    const float var = (red[4] + red[5] + red[6] + red[7]) * (1.0f / 1024.f);
    const float inv = rsqrtf(var + 1e-5f);
    float4 o4;
    o4.x = dx * inv; o4.y = dy * inv; o4.z = dz * inv; o4.w = dw * inv;
    ((float4*)(xout + (long)row * 1024))[tid] = o4;
    ushort4 ob;
    ob.x = f2bf(o4.x); ob.y = f2bf(o4.y); ob.z = f2bf(o4.z); ob.w = f2bf(o4.w);
    ((ushort4*)(xbout + (long)row * 1024))[tid] = ob;
}

// ---------------------------------------------------------------------------
extern "C" void kernel_launch(void* const* d_in, const int* in_sizes, int n_in,
                              void* d_out, int out_size, void* d_ws, size_t ws_size,
                              hipStream_t stream)
{
    const int*   seqp = (const int*)d_in[0];
    const int*   segp = (const int*)d_in[1];
    const float* tok  = (const float*)d_in[2];
    const float* sege = (const float*)d_in[3];
    const float* Wq = (const float*)d_in[4];  const float* bq = (const float*)d_in[5];
    const float* Wk = (const float*)d_in[6];  const float* bk = (const float*)d_in[7];
    const float* Wv = (const float*)d_in[8];  const float* bv = (const float*)d_in[9];
    const float* Wo = (const float*)d_in[10]; const float* bo = (const float*)d_in[11];
    const float* W1 = (const float*)d_in[12]; const float* b1 = (const float*)d_in[13];
    const float* W2 = (const float*)d_in[14]; const float* b2 = (const float*)d_in[15];

    // ---- workspace (lifetime-aliased; ~160 MB) ----
    char* w = (char*)d_ws;
    auto take = [&](size_t bytes) -> void* {
        void* p = (void*)w; w += (bytes + 255) & ~(size_t)255; return p;
    };
    float* x    = (float*)take(4096UL * 1024 * 4);     // 16 MB residual f32
    u16*   xb   = (u16*)  take(4096UL * 1024 * 2);     //  8 MB residual bf16
    float* tmp  = (float*)take(4096UL * 1024 * 4);     // 16 MB pre-LN f32
    u16*   R1   = (u16*)  take(128UL * 512 * 512 * 2); // 64 MB: S then hbuf
    u16*   qkv3 = (u16*)  take(3UL * 4096 * 1024 * 2); // 24 MB Q|K|V stacked
    u16*   ctx  = (u16*)  take(4096UL * 1024 * 2);     //  8 MB
    u16*   vt   = (u16*)  take(128UL * 64 * 512 * 2);  //  8 MB
    u16*   qkvw = (u16*)  take(3072UL * 1024 * 2);     //  6 MB W_{q,k,v}^T
    u16*   wo_t = (u16*)  take(1024UL * 1024 * 2);     //  2 MB
    u16*   w1_t = (u16*)  take(4096UL * 1024 * 2);     //  8 MB
    u16*   w2_t = (u16*)  take(1024UL * 4096 * 2);     //  8 MB
    float* bqkv = (float*)take(6UL * 3072 * 4);

    u16* S    = R1;              // scores [B,H,512,512] bf16
    u16* hbuf = R1;              // FFN hidden [4096,4096] (S dead by then)
    u16* Qb   = qkv3;            // [4096,1024] each; heads = contiguous chunks
    u16* Kb   = qkv3 + 4194304L;
    u16* Vb   = qkv3 + 8388608L;

    bconcat_kernel<<<72, 256, 0, stream>>>(bq, bk, bv, bqkv);
    embed_kernel<<<8192, 256, 0, stream>>>(seqp, segp, tok, sege, x, xb);

    for (int l = 0; l < 6; ++l) {
        // per-layer weight conversion (transpose + bf16)
        wconv_kernel<<<dim3(16, 16), 256, 0, stream>>>(Wq + (long)l * 1048576L, qkvw, 1024, 1024, 0);
        wconv_kernel<<<dim3(16, 16), 256, 0, stream>>>(Wk + (long)l * 1048576L, qkvw, 1024, 1024, 1024);
        wconv_kernel<<<dim3(16, 16), 256, 0, stream>>>(Wv + (long)l * 1048576L, qkvw, 1024, 1024, 2048);
        wconv_kernel<<<dim3(16, 16), 256, 0, stream>>>(Wo + (long)l * 1048576L, wo_t, 1024, 1024, 0);
        wconv_kernel<<<dim3(64, 16), 256, 0, stream>>>(W1 + (long)l * 4194304L, w1_t, 1024, 4096, 0);
        wconv_kernel<<<dim3(16, 64), 256, 0, stream>>>(W2 + (long)l * 4194304L, w2_t, 4096, 1024, 0);

        // fused QKV projection: [4096,1024] x [3072,1024]^T, epilogue routes
        // col>>10 to Qb/Kb/Vb (transpose-free head layout preserved)
        gemm_bt<2, 2, 4, 4, 5><<<dim3(32, 24, 1), 256, 0, stream>>>(
            xb, qkvw, qkv3, bqkv + l * 3072, nullptr,
            1024, 1024, 1024, 1024, 1, 0, 0, 0, 0, 0, 0, 1.f);

        // per-head V transpose: [512,64] -> [64,512]
        vtrans_kernel<<<dim3(8, 128), 256, 0, stream>>>(Vb, vt);

        // scores per (b,h): Q2[512,64] @ K2[512,64]^T * 0.125
        gemm_bt<2, 2, 4, 4, 3><<<dim3(4, 4, 128), 256, 0, stream>>>(
            Qb, Kb, S, nullptr, nullptr,
            64, 64, 64, 512,
            16, 524288L, 32768L, 524288L, 32768L, 4194304L, 262144L, 0.125f);

        // masked softmax (in place)
        softmax_kernel<<<16384, 256, 0, stream>>>(S, seqp);

        // context per (b,h): P[512,512] @ Vt[64,512]^T -> ctx chunk [512,64]
        gemm_bt<4, 1, 2, 4, 4><<<dim3(4, 1, 128), 256, 0, stream>>>(
            S, vt, ctx, nullptr, nullptr,
            512, 512, 512, 64,
            16, 4194304L, 262144L, 524288L, 32768L, 524288L, 32768L, 1.f);

        // output projection + bias + residual -> tmp fp32
        gemm_bt<2, 2, 4, 4, 1><<<dim3(32, 8, 1), 256, 0, stream>>>(
            ctx, wo_t, tmp, bo + l * 1024, x,
            1024, 1024, 1024, 1024, 1, 0, 0, 0, 0, 0, 0, 1.f);

        // LN -> x (f32 residual) + xb (bf16)
        ln_kernel<<<4096, 256, 0, stream>>>(tmp, x, xb);

        // FFN1 + exact GELU -> hbuf bf16 [4096,4096]  (overlays dead S)
        gemm_bt<2, 2, 4, 4, 2><<<dim3(32, 32, 1), 256, 0, stream>>>(
            xb, w1_t, hbuf, b1 + l * 4096, nullptr,
            1024, 1024, 1024, 4096, 1, 0, 0, 0, 0, 0, 0, 1.f);

        // FFN2 + bias + residual -> tmp fp32
        gemm_bt<2, 2, 4, 4, 1><<<dim3(32, 8, 1), 256, 0, stream>>>(
            hbuf, w2_t, tmp, b2 + l * 1024, x,
            4096, 4096, 4096, 1024, 1, 0, 0, 0, 0, 0, 0, 1.f);

        // LN -> x / d_out
        ln_kernel<<<4096, 256, 0, stream>>>(tmp, (l == 5) ? (float*)d_out : x, xb);
    }
}

// Round 7
// 1860.684 us; speedup vs baseline: 1.2210x; 1.0475x over previous
//
#include <hip/hip_runtime.h>
#include <cstdint>
#include <cstddef>

typedef unsigned short u16;
typedef __attribute__((ext_vector_type(8))) short short8;
typedef __attribute__((ext_vector_type(4))) float f32x4;

#define DEV __device__ __forceinline__

DEV float bf2f(u16 u) {
    union { float f; uint32_t i; } c; c.i = ((uint32_t)u) << 16; return c.f;
}
DEV u16 f2bf(float f) {
    union { float f; uint32_t i; } c; c.f = f;
    uint32_t r = c.i + 0x7FFF + ((c.i >> 16) & 1);
    return (u16)(r >> 16);
}

DEV void gload16(const void* g, void* l) {
    __builtin_amdgcn_global_load_lds(
        (const __attribute__((address_space(1))) void*)g,
        (__attribute__((address_space(3))) void*)l, 16, 0, 0);
}

template<int N> DEV void waitv() {
    if constexpr (N == 0)      asm volatile("s_waitcnt vmcnt(0)" ::: "memory");
    else if constexpr (N == 3) asm volatile("s_waitcnt vmcnt(3)" ::: "memory");
    else if constexpr (N == 4) asm volatile("s_waitcnt vmcnt(4)" ::: "memory");
    else if constexpr (N == 6) asm volatile("s_waitcnt vmcnt(6)" ::: "memory");
    else if constexpr (N == 8) asm volatile("s_waitcnt vmcnt(8)" ::: "memory");
    else                       asm volatile("s_waitcnt vmcnt(0)" ::: "memory");
}

// ---------------------------------------------------------------------------
// GEMM: C[M,N] = A[M,K] * Bt[N,K]^T (+ epilogue).
// 3-deep pipelined LDS staging with counted vmcnt + raw s_barrier (T3+T4-lite):
// per K-step: ds_read(k) | lgkmcnt(0) | BAR | stage(k+3) | MFMA | vmcnt(2L) | BAR.
// Own-wave vmcnt + barrier => all waves' tile-(k+1) loads complete, while
// tiles k+2,k+3 stay in flight (never drain to 0 in steady state).
// EPI 0: bf16 = acc+bias; 1: f32 = acc+bias+resid; 2: bf16 = gelu(acc+bias);
// EPI 3: bf16 = acc*scale; 4: bf16 = acc; 5: bf16 = acc+bias routed to 3
//        stacked [M,1024] buffers by col>>10 (fused QKV).
// ---------------------------------------------------------------------------
template<int WM, int WN, int MR, int NR, int EPI>
__global__ __launch_bounds__(256)
void gemm_bt(const u16* __restrict__ A, const u16* __restrict__ B, void* __restrict__ C,
             const float* __restrict__ bias, const float* __restrict__ resid,
             int K, int lda, int ldb, int ldc,
             int nh, long a_zb, long a_zh, long b_zb, long b_zh, long c_zb, long c_zh,
             float scale)
{
    static_assert(WM * WN == 4, "4 waves");
    constexpr int BM = WM * MR * 16;
    constexpr int BN = WN * NR * 16;
    constexpr int BK = 32;
    constexpr int NBUF = 3;
    __shared__ __align__(16) u16 As[NBUF * BM * BK];
    __shared__ __align__(16) u16 Bs[NBUF * BN * BK];

    const int tid  = threadIdx.x;
    const int lane = tid & 63;
    const int wid  = tid >> 6;
    const int zz = blockIdx.z;
    const int b = zz / nh, h = zz % nh;
    A += (long)b * a_zb + (long)h * a_zh;
    B += (long)b * b_zb + (long)h * b_zh;
    const long coff = (long)b * c_zb + (long)h * c_zh;
    const int m0 = blockIdx.x * BM, n0 = blockIdx.y * BN;

    f32x4 acc[MR][NR] = {};
    constexpr int AI = (BM * 4) / 256;   // 16B chunks per tile / threads
    constexpr int BI = (BN * 4) / 256;
    constexpr int L  = AI + BI;          // vmem loads per stage per thread

    const int wr = wid / WN, wc = wid % WN;
    const int lr = lane & 15, lk = lane >> 4;

    auto stage = [&](int buf, int k0) {
#pragma unroll
        for (int i = 0; i < AI; ++i) {
            int ch = (i << 8) + tid;
            const u16* g = A + (long)(m0 + (ch >> 2)) * lda + k0 + ((ch & 3) << 3);
            gload16(g, (char*)As + (size_t)buf * (BM * BK * 2) + ch * 16);
        }
#pragma unroll
        for (int i = 0; i < BI; ++i) {
            int ch = (i << 8) + tid;
            const u16* g = B + (long)(n0 + (ch >> 2)) * ldb + k0 + ((ch & 3) << 3);
            gload16(g, (char*)Bs + (size_t)buf * (BN * BK * 2) + ch * 16);
        }
    };

    const int nt = K >> 5;   // K-steps (all K are multiples of 32)

    // prologue: stage up to 3 tiles, then wait for tile 0 only
    if (nt > 0) stage(0, 0);
    if (nt > 1) stage(1, BK);
    if (nt > 2) stage(2, 2 * BK);
    if (nt > 2)      waitv<2 * L>();
    else if (nt > 1) waitv<L>();
    else             waitv<0>();
    __builtin_amdgcn_s_barrier();

    for (int k = 0; k < nt; ++k) {
        const int cur = k % 3;
        const u16* Ac = As + (size_t)cur * (BM * BK);
        const u16* Bc = Bs + (size_t)cur * (BN * BK);
        short8 af[MR], bf[NR];
#pragma unroll
        for (int m = 0; m < MR; ++m)
            af[m] = *(const short8*)(Ac + (wr * MR * 16 + m * 16 + lr) * BK + lk * 8);
#pragma unroll
        for (int n = 0; n < NR; ++n)
            bf[n] = *(const short8*)(Bc + (wc * NR * 16 + n * 16 + lr) * BK + lk * 8);

        // our reads of buf[cur] are complete; sync so no wave still reads it
        asm volatile("s_waitcnt lgkmcnt(0)" ::: "memory");
        __builtin_amdgcn_s_barrier();

        // refill buf[cur] with tile k+3 (stays in flight across next 2 steps)
        if (k + 3 < nt) stage(cur, (k + 3) * BK);

#pragma unroll
        for (int m = 0; m < MR; ++m)
#pragma unroll
            for (int n = 0; n < NR; ++n)
                acc[m][n] = __builtin_amdgcn_mfma_f32_16x16x32_bf16(af[m], bf[n], acc[m][n], 0, 0, 0);

        // ensure tile k+1 landed (own loads via vmcnt, all waves via barrier)
        if (k + 1 < nt) {
            if (k + 4 <= nt)      waitv<2 * L>();  // tiles k+2,k+3 in flight
            else if (k + 3 == nt) waitv<L>();      // tile k+2 in flight
            else                  waitv<0>();      // nothing beyond k+1
            __builtin_amdgcn_s_barrier();
        }
    }

    // epilogue: D lane layout: col = lane&15, row = (lane>>4)*4 + j
#pragma unroll
    for (int m = 0; m < MR; ++m) {
        const int rowb = m0 + wr * MR * 16 + m * 16 + (lane >> 4) * 4;
#pragma unroll
        for (int n = 0; n < NR; ++n) {
            const int col = n0 + wc * NR * 16 + n * 16 + lr;
            float bv = 0.f;
            if (EPI == 0 || EPI == 1 || EPI == 2 || EPI == 5) bv = bias[col];
#pragma unroll
            for (int j = 0; j < 4; ++j) {
                const long idx = coff + (long)(rowb + j) * ldc + col;
                float v = acc[m][n][j];
                if (EPI == 0) {
                    ((u16*)C)[idx] = f2bf(v + bv);
                } else if (EPI == 1) {
                    ((float*)C)[idx] = v + bv + resid[(long)(rowb + j) * ldc + col];
                } else if (EPI == 2) {
                    float t = v + bv;
                    ((u16*)C)[idx] = f2bf(0.5f * t * (1.0f + erff(t * 0.70710678118654752f)));
                } else if (EPI == 3) {
                    ((u16*)C)[idx] = f2bf(v * scale);
                } else if (EPI == 5) {
                    const long qidx = (long)(col >> 10) * 4194304L
                                    + (long)(rowb + j) * 1024 + (col & 1023);
                    ((u16*)C)[qidx] = f2bf(v + bv);
                } else {
                    ((u16*)C)[idx] = f2bf(v);
                }
            }
        }
    }
}

// ---------------------------------------------------------------------------
// weight transpose + f32->bf16: src fp32 [K,N] tile -> dst bf16 [row_off+N, K]
// ---------------------------------------------------------------------------
__global__ __launch_bounds__(256)
void wconv_kernel(const float* __restrict__ src, u16* __restrict__ dst,
                  int K, int N, int row_off)
{
    __shared__ __align__(16) float t[64][65];
    const float* s = src + (long)(blockIdx.y * 64) * N + blockIdx.x * 64;
    const int tid = threadIdx.x;
#pragma unroll
    for (int i = 0; i < 4; ++i) {
        int ch = (i << 8) + tid;
        int r = ch >> 4, c4 = ch & 15;
        float4 v = *(const float4*)(s + (long)r * N + c4 * 4);
        t[r][c4 * 4 + 0] = v.x; t[r][c4 * 4 + 1] = v.y;
        t[r][c4 * 4 + 2] = v.z; t[r][c4 * 4 + 3] = v.w;
    }
    __syncthreads();
    u16* d = dst + (long)(row_off + blockIdx.x * 64) * K + blockIdx.y * 64;
#pragma unroll
    for (int i = 0; i < 4; ++i) {
        int ch = (i << 8) + tid;
        int c = ch >> 4, k4 = ch & 15;
        ushort4 o;
        o.x = f2bf(t[k4 * 4 + 0][c]);
        o.y = f2bf(t[k4 * 4 + 1][c]);
        o.z = f2bf(t[k4 * 4 + 2][c]);
        o.w = f2bf(t[k4 * 4 + 3][c]);
        *(ushort4*)(d + (long)c * K + k4 * 4) = o;
    }
}

__global__ __launch_bounds__(256)
void bconcat_kernel(const float* __restrict__ bq, const float* __restrict__ bk,
                    const float* __restrict__ bv, float* __restrict__ out)
{
    int i = blockIdx.x * 256 + threadIdx.x;   // 6*3072 total
    int l = i / 3072, n = i % 3072;
    float v = (n < 1024) ? bq[l * 1024 + n]
            : (n < 2048) ? bk[l * 1024 + n - 1024]
                         : bv[l * 1024 + n - 2048];
    out[i] = v;
}

// ---------------------------------------------------------------------------
// embedding: x = tok_emb[seq] + PE + seg_emb[seg]; writes f32 + bf16
// ---------------------------------------------------------------------------
__global__ __launch_bounds__(256)
void embed_kernel(const int* __restrict__ seq, const int* __restrict__ seg,
                  const float* __restrict__ tok, const float* __restrict__ sege,
                  float* __restrict__ x, u16* __restrict__ xb)
{
    long i = ((long)blockIdx.x << 8) + threadIdx.x;  // B*L*512 pairs
    int d2 = (int)(i & 511);
    long bl = i >> 9;
    int l = (int)(bl & 511);
    int t = seq[bl];
    int g = seg[bl];
    float div = powf(10000.f, -(float)(2 * d2) * (1.0f / 1024.f));
    float arg = (float)l * div;
    float sv = sinf(arg), cv = cosf(arg);
    long toff = (long)t * 1024 + 2 * d2;
    long goff = (long)g * 1024 + 2 * d2;
    float x0 = tok[toff]     + sv + sege[goff];
    float x1 = tok[toff + 1] + cv + sege[goff + 1];
    long xo = (bl << 10) + 2 * d2;
    x[xo] = x0; x[xo + 1] = x1;
    xb[xo] = f2bf(x0); xb[xo + 1] = f2bf(x1);
}

// ---------------------------------------------------------------------------
// per-head V transpose: Vb flat per (b,h) = [512,64] row-major contiguous
//   -> vt per (b,h) = [64,512]
// ---------------------------------------------------------------------------
__global__ __launch_bounds__(256)
void vtrans_kernel(const u16* __restrict__ Vb, u16* __restrict__ vt)
{
    __shared__ __align__(16) u16 t[64][72];
    const int bh = blockIdx.y;           // 0..127
    const int l0 = blockIdx.x << 6;      // 0,64,...,448
    const u16* src = Vb + ((long)bh << 15) + (long)l0 * 64;   // contiguous 64x64
    const int tid = threadIdx.x;
#pragma unroll
    for (int i = 0; i < 2; ++i) {
        int ch = (i << 8) + tid;         // 0..511, 8 elems each
        int r = ch >> 3, c8 = ch & 7;
        short8 v = *(const short8*)(src + (long)r * 64 + (c8 << 3));
#pragma unroll
        for (int j = 0; j < 8; ++j) t[r][(c8 << 3) + j] = (u16)v[j];
    }
    __syncthreads();
    u16* d = vt + ((long)bh << 15) + l0;
#pragma unroll
    for (int i = 0; i < 2; ++i) {
        int ch = (i << 8) + tid;
        int dd = ch >> 3, l8 = ch & 7;
        short8 o;
#pragma unroll
        for (int j = 0; j < 8; ++j) o[j] = (short)t[(l8 << 3) + j][dd];
        *(short8*)(d + (long)dd * 512 + (l8 << 3)) = o;
    }
}

// ---------------------------------------------------------------------------
// masked softmax over rows of S [B*H*L, 512], bf16 in-place. one wave per row
// ---------------------------------------------------------------------------
__global__ __launch_bounds__(256)
void softmax_kernel(u16* __restrict__ S, const int* __restrict__ seq)
{
    long row = ((long)blockIdx.x << 2) + (threadIdx.x >> 6);
    int lane = threadIdx.x & 63;
    int b = (int)(row >> 13);   // / (H*L = 8192)
    u16* p = S + (row << 9);
    short8 raw = *(short8*)(p + (lane << 3));
    const int* sq = seq + (b << 9) + (lane << 3);
    float v[8];
#pragma unroll
    for (int i = 0; i < 8; ++i)
        v[i] = (sq[i] == 0) ? -1e9f : bf2f((u16)raw[i]);
    float mx = v[0];
#pragma unroll
    for (int i = 1; i < 8; ++i) mx = fmaxf(mx, v[i]);
#pragma unroll
    for (int o = 32; o; o >>= 1) mx = fmaxf(mx, __shfl_xor(mx, o));
    float e[8], sum = 0.f;
#pragma unroll
    for (int i = 0; i < 8; ++i) { e[i] = expf(v[i] - mx); sum += e[i]; }
#pragma unroll
    for (int o = 32; o; o >>= 1) sum += __shfl_xor(sum, o);
    float r = 1.0f / sum;
    short8 o8;
#pragma unroll
    for (int i = 0; i < 8; ++i) o8[i] = (short)f2bf(e[i] * r);
    *(short8*)(p + (lane << 3)) = o8;
}

// ---------------------------------------------------------------------------
// LayerNorm over D=1024, block per row; writes f32 (residual stream) + bf16
// ---------------------------------------------------------------------------
__global__ __launch_bounds__(256)
void ln_kernel(const float* __restrict__ in, float* __restrict__ xout, u16* __restrict__ xbout)
{
    const int row = blockIdx.x;
    const int tid = threadIdx.x;
    const float4 v = ((const float4*)(in + (long)row * 1024))[tid];
    float s = v.x + v.y + v.z + v.w;
#pragma unroll
    for (int o = 32; o; o >>= 1) s += __shfl_down(s, o);
    __shared__ float red[8];
    const int wid = tid >> 6, lane = tid & 63;
    if (lane == 0) red[wid] = s;
    __syncthreads();
    const float mean = (red[0] + red[1] + red[2] + red[3]) * (1.0f / 1024.f);
    const float dx = v.x - mean, dy = v.y - mean, dz = v.z - mean, dw = v.w - mean;
    float q = dx * dx + dy * dy + dz * dz + dw * dw;
#pragma unroll
    for (int o = 32; o; o >>= 1) q += __shfl_down(q, o);
    if (lane == 0) red[4 + wid] = q;
    __syncthreads();
    const float var = (red[4] + red[5] + red[6] + red[7]) * (1.0f / 1024.f);
    const float inv = rsqrtf(var + 1e-5f);
    float4 o4;
    o4.x = dx * inv; o4.y = dy * inv; o4.z = dz * inv; o4.w = dw * inv;
    ((float4*)(xout + (long)row * 1024))[tid] = o4;
    ushort4 ob;
    ob.x = f2bf(o4.x); ob.y = f2bf(o4.y); ob.z = f2bf(o4.z); ob.w = f2bf(o4.w);
    ((ushort4*)(xbout + (long)row * 1024))[tid] = ob;
}

// ---------------------------------------------------------------------------
extern "C" void kernel_launch(void* const* d_in, const int* in_sizes, int n_in,
                              void* d_out, int out_size, void* d_ws, size_t ws_size,
                              hipStream_t stream)
{
    const int*   seqp = (const int*)d_in[0];
    const int*   segp = (const int*)d_in[1];
    const float* tok  = (const float*)d_in[2];
    const float* sege = (const float*)d_in[3];
    const float* Wq = (const float*)d_in[4];  const float* bq = (const float*)d_in[5];
    const float* Wk = (const float*)d_in[6];  const float* bk = (const float*)d_in[7];
    const float* Wv = (const float*)d_in[8];  const float* bv = (const float*)d_in[9];
    const float* Wo = (const float*)d_in[10]; const float* bo = (const float*)d_in[11];
    const float* W1 = (const float*)d_in[12]; const float* b1 = (const float*)d_in[13];
    const float* W2 = (const float*)d_in[14]; const float* b2 = (const float*)d_in[15];

    // ---- workspace (lifetime-aliased; ~160 MB) ----
    char* w = (char*)d_ws;
    auto take = [&](size_t bytes) -> void* {
        void* p = (void*)w; w += (bytes + 255) & ~(size_t)255; return p;
    };
    float* x    = (float*)take(4096UL * 1024 * 4);     // 16 MB residual f32
    u16*   xb   = (u16*)  take(4096UL * 1024 * 2);     //  8 MB residual bf16
    float* tmp  = (float*)take(4096UL * 1024 * 4);     // 16 MB pre-LN f32
    u16*   R1   = (u16*)  take(128UL * 512 * 512 * 2); // 64 MB: S then hbuf
    u16*   qkv3 = (u16*)  take(3UL * 4096 * 1024 * 2); // 24 MB Q|K|V stacked
    u16*   ctx  = (u16*)  take(4096UL * 1024 * 2);     //  8 MB
    u16*   vt   = (u16*)  take(128UL * 64 * 512 * 2);  //  8 MB
    u16*   qkvw = (u16*)  take(3072UL * 1024 * 2);     //  6 MB W_{q,k,v}^T
    u16*   wo_t = (u16*)  take(1024UL * 1024 * 2);     //  2 MB
    u16*   w1_t = (u16*)  take(4096UL * 1024 * 2);     //  8 MB
    u16*   w2_t = (u16*)  take(1024UL * 4096 * 2);     //  8 MB
    float* bqkv = (float*)take(6UL * 3072 * 4);

    u16* S    = R1;              // scores [B,H,512,512] bf16
    u16* hbuf = R1;              // FFN hidden [4096,4096] (S dead by then)
    u16* Qb   = qkv3;            // [4096,1024] each; heads = contiguous chunks
    u16* Kb   = qkv3 + 4194304L;
    u16* Vb   = qkv3 + 8388608L;

    bconcat_kernel<<<72, 256, 0, stream>>>(bq, bk, bv, bqkv);
    embed_kernel<<<8192, 256, 0, stream>>>(seqp, segp, tok, sege, x, xb);

    for (int l = 0; l < 6; ++l) {
        // per-layer weight conversion (transpose + bf16)
        wconv_kernel<<<dim3(16, 16), 256, 0, stream>>>(Wq + (long)l * 1048576L, qkvw, 1024, 1024, 0);
        wconv_kernel<<<dim3(16, 16), 256, 0, stream>>>(Wk + (long)l * 1048576L, qkvw, 1024, 1024, 1024);
        wconv_kernel<<<dim3(16, 16), 256, 0, stream>>>(Wv + (long)l * 1048576L, qkvw, 1024, 1024, 2048);
        wconv_kernel<<<dim3(16, 16), 256, 0, stream>>>(Wo + (long)l * 1048576L, wo_t, 1024, 1024, 0);
        wconv_kernel<<<dim3(64, 16), 256, 0, stream>>>(W1 + (long)l * 4194304L, w1_t, 1024, 4096, 0);
        wconv_kernel<<<dim3(16, 64), 256, 0, stream>>>(W2 + (long)l * 4194304L, w2_t, 4096, 1024, 0);

        // fused QKV projection: [4096,1024] x [3072,1024]^T, epilogue routes
        // col>>10 to Qb/Kb/Vb (transpose-free head layout preserved)
        gemm_bt<2, 2, 4, 4, 5><<<dim3(32, 24, 1), 256, 0, stream>>>(
            xb, qkvw, qkv3, bqkv + l * 3072, nullptr,
            1024, 1024, 1024, 1024, 1, 0, 0, 0, 0, 0, 0, 1.f);

        // per-head V transpose: [512,64] -> [64,512]
        vtrans_kernel<<<dim3(8, 128), 256, 0, stream>>>(Vb, vt);

        // scores per (b,h): Q2[512,64] @ K2[512,64]^T * 0.125
        gemm_bt<2, 2, 4, 4, 3><<<dim3(4, 4, 128), 256, 0, stream>>>(
            Qb, Kb, S, nullptr, nullptr,
            64, 64, 64, 512,
            16, 524288L, 32768L, 524288L, 32768L, 4194304L, 262144L, 0.125f);

        // masked softmax (in place)
        softmax_kernel<<<16384, 256, 0, stream>>>(S, seqp);

        // context per (b,h): P[512,512] @ Vt[64,512]^T -> ctx chunk [512,64]
        gemm_bt<4, 1, 2, 4, 4><<<dim3(4, 1, 128), 256, 0, stream>>>(
            S, vt, ctx, nullptr, nullptr,
            512, 512, 512, 64,
            16, 4194304L, 262144L, 524288L, 32768L, 524288L, 32768L, 1.f);

        // output projection + bias + residual -> tmp fp32
        gemm_bt<2, 2, 4, 4, 1><<<dim3(32, 8, 1), 256, 0, stream>>>(
            ctx, wo_t, tmp, bo + l * 1024, x,
            1024, 1024, 1024, 1024, 1, 0, 0, 0, 0, 0, 0, 1.f);

        // LN -> x (f32 residual) + xb (bf16)
        ln_kernel<<<4096, 256, 0, stream>>>(tmp, x, xb);

        // FFN1 + exact GELU -> hbuf bf16 [4096,4096]  (overlays dead S)
        gemm_bt<2, 2, 4, 4, 2><<<dim3(32, 32, 1), 256, 0, stream>>>(
            xb, w1_t, hbuf, b1 + l * 4096, nullptr,
            1024, 1024, 1024, 4096, 1, 0, 0, 0, 0, 0, 0, 1.f);

        // FFN2 + bias + residual -> tmp fp32
        gemm_bt<2, 2, 4, 4, 1><<<dim3(32, 8, 1), 256, 0, stream>>>(
            hbuf, w2_t, tmp, b2 + l * 1024, x,
            4096, 4096, 4096, 1024, 1, 0, 0, 0, 0, 0, 0, 1.f);

        // LN -> x / d_out
        ln_kernel<<<4096, 256, 0, stream>>>(tmp, (l == 5) ? (float*)d_out : x, xb);
    }
}